// Round 10
// baseline (349.243 us; speedup 1.0000x reference)
//
#include <hip/hip_runtime.h>

// ECA / frequency-channel-attention for MI355X (gfx950).
// Two-pass DCT: pass1 P=X·D^T per (b,c) -> PG (fragment-ordered, in d_out scratch)
// pass2 E+=|D·P| (no LDS, no barriers) -> reduce -> top16+MLP -> scale.

typedef __attribute__((ext_vector_type(8))) _Float16 half8;
typedef __attribute__((ext_vector_type(16))) float f32x16;

#define NCH 32   // channel chunks (pass2) per batch
#define CPB2 4   // channels per pass2 block

#define Z16 {0.f,0.f,0.f,0.f,0.f,0.f,0.f,0.f,0.f,0.f,0.f,0.f,0.f,0.f,0.f,0.f}

// XOR-swizzled byte offset for a [128][128] 2-byte LDS tile (guide G4/T2).
#define SWZ(row, c) (((((row) * 128 + (c)) * 2)) ^ (((row) & 7) << 4))

__device__ __forceinline__ unsigned short f2h(float f) {
    union { _Float16 h; unsigned short u; } cv;
    cv.h = (_Float16)f;
    return cv.u;
}
__device__ __forceinline__ unsigned int pack2(float a, float b) {
    return (unsigned int)f2h(a) | ((unsigned int)f2h(b) << 16);
}

// Packed MFMA-fragment layout: Dp[kk][hi][r][j] = D[r][16*kk+8*hi+j]
// D[r][c] = s_r * cos(pi*(2c+1)r / 256), s_0 = sqrt(1/128), else 1/8.
__global__ __launch_bounds__(256) void dct_prep(unsigned short* __restrict__ Dp) {
    int i = blockIdx.x * 256 + threadIdx.x;   // 0..16383
    int j = i & 7, r = (i >> 3) & 127, hi = (i >> 10) & 1, kk = i >> 11;
    int c = kk * 16 + hi * 8 + j;
    float s = (r == 0) ? 0.08838834764831845f : 0.125f;
    float ang = (float)((2 * c + 1) * r) * 0.012271846303085130f; // * pi/256
    Dp[i] = f2h(s * cosf(ang));
}

// ---- pass 1: per (b,c) slice, P = X @ D^T, write PG in fragment order.
// PG slice layout (halves): PG[hcg][wp][j] = P[8*hcg + j][wp], hcg=0..15, wp=0..127.
__global__ __launch_bounds__(512) void dct_pass1(
    const float* __restrict__ x, const unsigned short* __restrict__ Dp,
    unsigned short* __restrict__ PG)
{
    __shared__ __attribute__((aligned(16))) unsigned short Xs[128 * 128];

    const int b = blockIdx.x;
    const int c = blockIdx.y;
    const int tid = threadIdx.x;
    const int lane = tid & 63;
    const int wid = tid >> 6;
    const int wm = wid >> 1;       // 0..3
    const int wn = wid & 1;        // 0..1
    const int l31 = lane & 31;
    const int hi = lane >> 5;

    const float4* xb4 = (const float4*)(x + (((size_t)(b * 128 + c)) << 14));

    // stage X slice (f32 -> f16) into swizzled LDS
#pragma unroll
    for (int i = 0; i < 8; ++i) {
        float4 v = xb4[i * 512 + tid];
        int fidx = i * 512 + tid;
        int row = fidx >> 5, cc = (fidx & 31) << 2;
        uint2 u; u.x = pack2(v.x, v.y); u.y = pack2(v.z, v.w);
        *(uint2*)((char*)Xs + SWZ(row, cc)) = u;
    }
    __syncthreads();

    const int rowX = 32 * wm + l31;   // X row (H)
    const int k2a = 64 * wn + l31;    // output col (w')
    const unsigned short* dB0 = Dp + k2a * 8;
    const unsigned short* dB1 = Dp + (k2a + 32) * 8;

    f32x16 acc0 = Z16, acc1 = Z16;
#pragma unroll
    for (int kk = 0; kk < 8; ++kk) {
        int c0 = kk * 16 + hi * 8;
        int kb = (kk * 2 + hi) << 10;
        half8 aX = *(const half8*)((const char*)Xs + SWZ(rowX, c0));
        half8 bD0 = *(const half8*)(const void*)(dB0 + kb);
        half8 bD1 = *(const half8*)(const void*)(dB1 + kb);
        acc0 = __builtin_amdgcn_mfma_f32_32x32x16_f16(aX, bD0, acc0, 0, 0, 0);
        acc1 = __builtin_amdgcn_mfma_f32_32x32x16_f16(aX, bD1, acc1, 0, 0, 0);
    }
    __syncthreads();   // all Xs reads done -> reuse buffer for P^T

    // write P^T into Xs: row = w' (k2a), col = H. C/D: col=lane&31, row=(r&3)+8*(r>>2)+4*hi
#pragma unroll
    for (int g = 0; g < 4; ++g) {
        int h0 = 32 * wm + 8 * g + 4 * hi;
        uint2 v0; v0.x = pack2(acc0[4 * g + 0], acc0[4 * g + 1]);
        v0.y = pack2(acc0[4 * g + 2], acc0[4 * g + 3]);
        *(uint2*)((char*)Xs + SWZ(k2a, h0)) = v0;
        uint2 v1; v1.x = pack2(acc1[4 * g + 0], acc1[4 * g + 1]);
        v1.y = pack2(acc1[4 * g + 2], acc1[4 * g + 3]);
        *(uint2*)((char*)Xs + SWZ(k2a + 32, h0)) = v1;
    }
    __syncthreads();

    // streamout: PG[hcg][wp][0..7] = PT_lds[wp][8*hcg .. +8), coalesced 16B stores
    unsigned short* pgs = PG + (((size_t)(b * 128 + c)) << 14);
#pragma unroll
    for (int i = 0; i < 4; ++i) {
        int chunk = i * 512 + tid;          // 0..2047
        int hcg = chunk >> 7, wp = chunk & 127;
        uint4 v = *(const uint4*)((const char*)Xs + SWZ(wp, hcg * 8));
        *(uint4*)(pgs + (size_t)chunk * 8) = v;
    }
}

// ---- pass 2: E += |D @ P| over CPB2 channels. No LDS, no barriers.
__global__ __launch_bounds__(512) void dct_pass2(
    const unsigned short* __restrict__ PG, const unsigned short* __restrict__ Dp,
    float* __restrict__ energy, float* __restrict__ partial)
{
    const int b = blockIdx.x;
    const int chunk = blockIdx.y;
    const int tid = threadIdx.x;
    const int lane = tid & 63;
    const int wid = tid >> 6;
    const int wm = wid >> 1;
    const int wn = wid & 1;
    const int l31 = lane & 31;
    const int hi = lane >> 5;

    const int rowX = 32 * wm + l31;   // D row (h')
    const int k2a = 64 * wn + l31;    // output col (w')
    const unsigned short* dA = Dp + rowX * 8;

    float en0[16], en1[16];
#pragma unroll
    for (int r = 0; r < 16; ++r) { en0[r] = 0.f; en1[r] = 0.f; }

    for (int s = 0; s < CPB2; ++s) {
        const unsigned short* pgs =
            PG + (((size_t)(b * 128 + chunk * CPB2 + s)) << 14);
        const unsigned short* pB0 = pgs + (size_t)k2a * 8;
        const unsigned short* pB1 = pB0 + 32 * 8;

        f32x16 d0 = Z16, d1 = Z16;
#pragma unroll
        for (int kk = 0; kk < 8; ++kk) {
            int kb = (kk * 2 + hi) << 10;
            half8 aD = *(const half8*)(const void*)(dA + kb);
            half8 b0 = *(const half8*)(const void*)(pB0 + kb);
            half8 b1 = *(const half8*)(const void*)(pB1 + kb);
            d0 = __builtin_amdgcn_mfma_f32_32x32x16_f16(aD, b0, d0, 0, 0, 0);
            d1 = __builtin_amdgcn_mfma_f32_32x32x16_f16(aD, b1, d1, 0, 0, 0);
        }
#pragma unroll
        for (int r = 0; r < 16; ++r) { en0[r] += fabsf(d0[r]); en1[r] += fabsf(d1[r]); }
    }

    if (partial) {
        float* pb = partial + (((size_t)(b * NCH + chunk)) << 14);
#pragma unroll
        for (int r = 0; r < 16; ++r) {
            int row = 32 * wm + (r & 3) + 8 * (r >> 2) + 4 * hi;
            int idx = row * 128 + k2a;
            pb[idx] = en0[r];
            pb[idx + 32] = en1[r];
        }
    } else {
        float* eb = energy + ((size_t)b << 14);
#pragma unroll
        for (int r = 0; r < 16; ++r) {
            int row = 32 * wm + (r & 3) + 8 * (r >> 2) + 4 * hi;
            int idx = row * 128 + k2a;
            atomicAdd(&eb[idx], en0[r]);
            atomicAdd(&eb[idx + 32], en1[r]);
        }
    }
}

__global__ __launch_bounds__(256) void reduce_energy(
    const float* __restrict__ partial, float* __restrict__ energy)
{
    int g = blockIdx.x * 256 + threadIdx.x;   // 0..262143
    int b = g >> 14, i = g & 16383;
    const float* p = partial + (((size_t)b * NCH) << 14) + i;
    float s = 0.f;
#pragma unroll
    for (int ch = 0; ch < NCH; ++ch) s += p[(size_t)ch << 14];
    energy[g] = s;   // sum over C (divide by 128 later)
}

// one block per batch, 1024 threads: iterative top-16 via register scan +
// wave shuffle reduce + 16-entry LDS final (2 barriers/round).
__global__ __launch_bounds__(1024) void topk_mlp(
    const float* __restrict__ energy,
    const float* __restrict__ w1, const float* __restrict__ b1,
    const float* __restrict__ w2, const float* __restrict__ b2,
    float* __restrict__ att)
{
    __shared__ float wv[16];
    __shared__ int   wi[16];
    __shared__ float winv_s;
    __shared__ int   wini_s;
    __shared__ float topv[16];
    int b = blockIdx.x, t = threadIdx.x;
    int lane = t & 63, wid = t >> 6;
    const float* eb = energy + ((size_t)b << 14);

    float v[16];
#pragma unroll
    for (int k = 0; k < 16; ++k) v[k] = eb[k * 1024 + t];
    unsigned mask = 0xFFFFu;

    for (int j = 0; j < 16; ++j) {
        float mv = -1e30f; int mi = 0;
#pragma unroll
        for (int k = 0; k < 16; ++k) {
            if ((mask >> k) & 1u) {
                float c = v[k];
                if (c > mv) { mv = c; mi = k * 1024 + t; }
            }
        }
#pragma unroll
        for (int off = 32; off >= 1; off >>= 1) {
            float ov = __shfl_down(mv, off);
            int   oi = __shfl_down(mi, off);
            if (ov > mv) { mv = ov; mi = oi; }
        }
        if (lane == 0) { wv[wid] = mv; wi[wid] = mi; }
        __syncthreads();
        if (t == 0) {
            float bv = wv[0]; int bi = wi[0];
#pragma unroll
            for (int w = 1; w < 16; ++w)
                if (wv[w] > bv) { bv = wv[w]; bi = wi[w]; }
            winv_s = bv; wini_s = bi;
            topv[j] = bv * (1.0f / 128.0f);   // mean over C
        }
        __syncthreads();
        int gw = wini_s;
        if (t == (gw & 1023)) mask &= ~(1u << (gw >> 10));
    }

    if (t == 0) {
        float z = b2[0];
#pragma unroll
        for (int jj = 0; jj < 4; ++jj) {
            float a = b1[jj];
#pragma unroll
            for (int i = 0; i < 16; ++i) a += topv[i] * w1[i * 4 + jj];
            a = fmaxf(a, 0.0f);
            z += a * w2[jj];
        }
        att[b] = 1.0f / (1.0f + expf(-z));
    }
}

__global__ __launch_bounds__(256) void scale_kernel(
    const float4* __restrict__ x4, const float* __restrict__ att,
    float4* __restrict__ out4, int n4)
{
    int i = blockIdx.x * 256 + threadIdx.x;
    int stride = gridDim.x * 256;
    for (; i < n4; i += stride) {
        float a = att[i >> 19];   // 2^19 float4 per batch
        float4 v = x4[i];
        v.x *= a; v.y *= a; v.z *= a; v.w *= a;
        out4[i] = v;
    }
}

extern "C" void kernel_launch(void* const* d_in, const int* in_sizes, int n_in,
                              void* d_out, int out_size, void* d_ws, size_t ws_size,
                              hipStream_t stream) {
    const float* x  = (const float*)d_in[0];
    const float* w1 = (const float*)d_in[1];
    const float* b1 = (const float*)d_in[2];
    const float* w2 = (const float*)d_in[3];
    const float* b2 = (const float*)d_in[4];

    char* wsb = (char*)d_ws;
    unsigned short* Dp = (unsigned short*)wsb;               // 32 KB  @ 0
    float* energy = (float*)(wsb + (1 << 15));               // 1 MB   @ 32 KB
    float* att    = (float*)(wsb + (1 << 15) + (1 << 20));   // 64 B
    float* partial = (float*)(wsb + (1 << 21));              // 32 MB  @ 2 MB
    size_t need_partial = (size_t)(1 << 21) + (size_t)16 * NCH * 16384 * 4;
    bool use_partial = (ws_size >= need_partial);

    // PG (64 MB, f16 fragment-ordered P) lives in d_out scratch space;
    // scale_kernel fully overwrites d_out afterwards.
    unsigned short* PG = (unsigned short*)d_out;

    dct_prep<<<64, 256, 0, stream>>>(Dp);
    if (!use_partial) hipMemsetAsync(energy, 0, (size_t)16 * 16384 * 4, stream);

    dim3 g1(16, 128);
    dct_pass1<<<g1, 512, 0, stream>>>(x, Dp, PG);
    dim3 g2(16, NCH);
    dct_pass2<<<g2, 512, 0, stream>>>(PG, Dp, energy,
                                      use_partial ? partial : (float*)nullptr);
    if (use_partial) reduce_energy<<<1024, 256, 0, stream>>>(partial, energy);

    topk_mlp<<<16, 1024, 0, stream>>>(energy, w1, b1, w2, b2, att);
    scale_kernel<<<2048, 256, 0, stream>>>((const float4*)x, att,
                                           (float4*)d_out, out_size / 4);
}